// Round 3
// baseline (1405148.633 us; speedup 1.0000x reference)
//
#include <hip/hip_runtime.h>

#define NROWS 2048
#define DR2   512
#define TSTEPS 64
#define NK    ((size_t)NROWS * DR2)          // elements per [N,512] slice
#define NWG   256                            // persistent grid: 1 WG/CU (128 KB LDS)

typedef _Float16 half8 __attribute__((ext_vector_type(8)));
typedef float floatx4 __attribute__((ext_vector_type(4)));

// Async global->LDS, 16 B/lane. LDS base wave-uniform; HW scatters lane i at
// base + 16*i. Bank-conflict swizzle is applied on the GLOBAL address side.
static __device__ __forceinline__ void gload_lds16(const _Float16* g, _Float16* l) {
    __builtin_amdgcn_global_load_lds(
        (const __attribute__((address_space(1))) unsigned int*)g,
        (__attribute__((address_space(3))) unsigned int*)l,
        16, 0, 0);
}
// SC0 variant for h: lines are produced each step by OTHER CUs of the same
// XCD; sc0 bypasses this CU's (potentially stale) L1 and reads the XCD L2,
// which is the point of coherence for same-XCD producers.
static __device__ __forceinline__ void gload_lds16_sc0(const _Float16* g, _Float16* l) {
    __builtin_amdgcn_global_load_lds(
        (const __attribute__((address_space(1))) unsigned int*)g,
        (__attribute__((address_space(3))) unsigned int*)l,
        16, 0, 1);
}

// L2-level flag ops: sc0 only (bypass L1, served by the XCD's L2). No sc1 —
// barrier state never touches L3, and never needs wbl2/inv cache maintenance.
static __device__ __forceinline__ void st_flag_l2(unsigned* p, unsigned v) {
    asm volatile("global_store_dword %0, %1, off sc0" :: "v"(p), "v"(v) : "memory");
}
static __device__ __forceinline__ unsigned ld_flag_l2(const unsigned* p) {
    unsigned v;
    asm volatile("global_load_dword %0, %1, off sc0\n\ts_waitcnt vmcnt(0)"
                 : "=v"(v) : "v"(p) : "memory");
    return v;
}

// Wt[j][kk] = w1[kk][j], f16, j in [0,512), kk in [0,1024).
// kk<512 multiplies h (top), kk>=512 multiplies static (bottom).
// Also zeroes the barrier flags / claim counters (visible to run_steps via
// the kernel-boundary L2 writeback+invalidate).
__global__ void prep_w(const float* __restrict__ w1, _Float16* __restrict__ Wt,
                       unsigned* bar) {
    if (blockIdx.x == 0)
        for (int i = threadIdx.x; i < 640; i += 256) bar[i] = 0u;
    int idx = blockIdx.x * 256 + threadIdx.x;   // = j*1024 + kk
    int kk = idx & 1023;
    int j  = idx >> 10;
    Wt[idx] = (_Float16)w1[kk * DR2 + j];
}

// h16 = (f16)h0 ; out0[0] = h0 (reference stores h0, NOT states[0])
__global__ void prep_h0(const float* __restrict__ h0, _Float16* __restrict__ h16,
                        float* __restrict__ out0) {
    int idx = blockIdx.x * 256 + threadIdx.x;   // per float4
    float4 v = ((const float4*)h0)[idx];
    ((float4*)out0)[idx] = v;
    union { uint2 u; _Float16 h[4]; } p;
    p.h[0] = (_Float16)v.x; p.h[1] = (_Float16)v.y;
    p.h[2] = (_Float16)v.z; p.h[3] = (_Float16)v.w;
    ((uint2*)h16)[idx] = p.u;
}

// ---------------------------------------------------------------------------
// Persistent kernel, XCD-local recurrence. Each physical XCD (read via
// HW_REG_XCC_ID, slot claimed by atomicAdd) owns 256 rows: 32 WGs = 16
// j-blocks x 2 row-groups of 128. h ping-pong stays inside the XCD's L2;
// the per-step barrier is 32 sc0 epoch-flag stores + a wave-parallel sc0
// poll — no fences, no L3, no cache-maintenance ops, no RMW chains.
// mm = [h | static_t] @ w1 (K=1024), Wres resident in LDS for all 64 steps.
// ---------------------------------------------------------------------------
__global__ __launch_bounds__(512, 1) void run_steps(
    const float* __restrict__ thr,       // [T,N]
    const _Float16* __restrict__ Wt,     // [512][1024]
    const float* __restrict__ h0,        // [N,512] f32
    const float* __restrict__ sta,       // [T,N,512] f32
    _Float16* __restrict__ hb0,          // [N,512] f16 ping
    _Float16* __restrict__ hb1,          // [N,512] f16 pong
    float* __restrict__ out0, float* __restrict__ out1, float* __restrict__ out2,
    unsigned* bar)                       // [0..511] flags, [512..519] claim
{
    __shared__ _Float16 Wres[32 * 1024];     // 64 KB, resident all 64 steps
    __shared__ _Float16 Abuf[2][128 * 128];  // 2 x 32 KB, K-phase double buffer
    __shared__ unsigned slot_sh;

    const int tid = threadIdx.x, lane = tid & 63, wv = tid >> 6;
    const int lm = lane & 15, quad = lane >> 4;

    // physical placement: which XCD is this WG on?  (HW_REG_XCC_ID = id 20,
    // offset 0, size 32 -> imm (31<<11)|20 = 63508; m09-verified on MI355X)
    const unsigned xcd = (unsigned)__builtin_amdgcn_s_getreg(63508) & 7u;
    if (tid == 0) slot_sh = atomicAdd(bar + 512 + xcd, 1u);   // device-scope
    __syncthreads();
    const unsigned slot = slot_sh;                 // 0..31 within this XCD
    const int j0 = (int)(slot & 15) * 32;
    const int n0 = ((int)xcd * 2 + (int)(slot >> 4)) * 128;
    unsigned* flags = bar + xcd * 64;

    // one-time: full-W residency (32 j-rows x K=1024, swizzled global source)
    #pragma unroll
    for (int i = 0; i < 8; ++i) {
        int idx = i * 8 + wv;                      // 0..63
        int r = idx >> 1, hh = idx & 1;
        gload_lds16(Wt + (size_t)(j0 + r) * 1024 + hh * 512 + (lane ^ (r & 7)) * 8,
                    Wres + r * 1024 + hh * 512);
    }

    const int nb = n0 + wv * 16 + quad * 4;        // + r
    const int jb = j0 + lm;                        // + tj*16
    const int ra = wv * 16 + lm;                   // A row for MFMA reads
    float thv[4], thvn[4], hrv[2][4];
    #pragma unroll
    for (int r = 0; r < 4; ++r) {
        thv[r] = thr[nb + r];                      // t = 0
        #pragma unroll
        for (int tj = 0; tj < 2; ++tj)             // f16-roundtripped gate operand
            hrv[tj][r] = (float)(_Float16)h0[(size_t)(nb + r) * DR2 + jb + tj * 16];
    }

    const float DECAY = 0.60653065971263342f;

    #pragma unroll 1
    for (int t = 0; t < TSTEPS; ++t) {
        const _Float16* hcur = (t & 1) ? hb1 : hb0;
        _Float16*       hnx  = (t & 1) ? hb0 : hb1;
        const float*    stat = sta + (size_t)t * NK;

        // stage K-phase 0 of A (h rows n0..n0+127, K 0..127)
        #pragma unroll
        for (int i = 0; i < 4; ++i) {
            int rp = wv * 16 + i * 4;
            int r  = rp + (lane >> 4);
            int c  = (lane & 15) ^ (r & 7);
            gload_lds16_sc0(hcur + (size_t)(n0 + r) * DR2 + c * 8, &Abuf[0][rp * 128]);
        }
        __syncthreads();    // also drains Wres loads on t=0

        floatx4 acc[2] = {};

        #pragma unroll
        for (int p = 0; p < 8; ++p) {
            float4 pre[8];
            if (p < 3) {                           // prefetch next h phase
                #pragma unroll
                for (int i = 0; i < 4; ++i) {
                    int rp = wv * 16 + i * 4;
                    int r  = rp + (lane >> 4);
                    int c  = (lane & 15) ^ (r & 7);
                    gload_lds16_sc0(hcur + (size_t)(n0 + r) * DR2 + (p + 1) * 128 + c * 8,
                                    &Abuf[(p + 1) & 1][rp * 128]);
                }
            } else if (p < 7) {                    // issue static f32 loads early
                #pragma unroll
                for (int q = 0; q < 4; ++q) {
                    int cidx = q * 512 + tid;      // 0..2047 = 128 rows x 16 chunks
                    int r = cidx >> 4, c16 = cidx & 15;
                    int k8 = c16 ^ (r & 7);
                    const float* g = stat + (size_t)(n0 + r) * DR2 + (p - 3) * 128 + k8 * 8;
                    pre[q * 2]     = *(const float4*)g;
                    pre[q * 2 + 1] = *(const float4*)(g + 4);
                }
            }
            if (p == 0 && t < TSTEPS - 1) {        // prefetch next-step thr
                #pragma unroll
                for (int r = 0; r < 4; ++r)
                    thvn[r] = thr[(t + 1) * NROWS + nb + r];
            }

            const _Float16* A = Abuf[p & 1];
            #pragma unroll
            for (int ks = 0; ks < 4; ++ks) {
                int c8 = ks * 4 + quad;            // phase-local chunk 0..15
                int cg = p * 16 + c8;              // global K chunk 0..127
                half8 a  = *(const half8*)(A + ra * 128 + ((c8 ^ (ra & 7)) << 3));
                half8 b0 = *(const half8*)(Wres + lm * 1024 + ((cg ^ (lm & 7)) << 3));
                half8 b1 = *(const half8*)(Wres + (lm + 16) * 1024 + ((cg ^ (lm & 7)) << 3));
                acc[0] = __builtin_amdgcn_mfma_f32_16x16x32_f16(a, b0, acc[0], 0, 0, 0);
                acc[1] = __builtin_amdgcn_mfma_f32_16x16x32_f16(a, b1, acc[1], 0, 0, 0);
            }

            if (p >= 3 && p < 7) {                 // cvt + ds_write static phase
                #pragma unroll
                for (int q = 0; q < 4; ++q) {
                    int cidx = q * 512 + tid;
                    int r = cidx >> 4, c16 = cidx & 15;
                    float4 lo = pre[q * 2], hi = pre[q * 2 + 1];
                    union { half8 v; _Float16 h[8]; } u;
                    u.h[0]=(_Float16)lo.x; u.h[1]=(_Float16)lo.y;
                    u.h[2]=(_Float16)lo.z; u.h[3]=(_Float16)lo.w;
                    u.h[4]=(_Float16)hi.x; u.h[5]=(_Float16)hi.y;
                    u.h[6]=(_Float16)hi.z; u.h[7]=(_Float16)hi.w;
                    *(half8*)(&Abuf[(p + 1) & 1][r * 128 + (c16 << 3)]) = u.v;
                }
            }
            if (p < 7) __syncthreads();
        }

        // epilogue: gate; outputs written immediately (pure, no aliasing)
        #pragma unroll
        for (int r = 0; r < 4; ++r) {
            float th = thv[r], om = 1.0f - th;
            #pragma unroll
            for (int tj = 0; tj < 2; ++tj) {
                float z  = acc[tj][r] * th + hrv[tj][r] * om;
                float hn = DECAY / (1.0f + __expf(-z));
                _Float16 h16 = (_Float16)hn;
                if (t < TSTEPS - 1)                // next step's input (local L2)
                    hnx[(size_t)(nb + r) * DR2 + jb + tj * 16] = h16;
                if (t >= 1) {
                    size_t o = ((size_t)t * NROWS + nb + r) * DR2 + jb + tj * 16;
                    __builtin_nontemporal_store(hn, out0 + o);
                    __builtin_nontemporal_store(hn - hrv[tj][r], out2 + (o - NK));
                }
                if (t == TSTEPS - 1)
                    __builtin_nontemporal_store(
                        hn, out1 + (size_t)(nb + r) * DR2 + jb + tj * 16);
                hrv[tj][r] = (float)h16;           // f16-roundtripped carry
            }
            if (t < TSTEPS - 1) thv[r] = thvn[r];
        }

        // ---- XCD-local barrier: epoch flags in the local L2, no fences ----
        if (t < TSTEPS - 1) {
            __syncthreads();                       // drains vmcnt: all h-stores in L2
            if (tid == 0) st_flag_l2(flags + slot, (unsigned)(t + 1));
            if (tid < 64) {                        // wave 0 polls all 32 slots
                const unsigned* fp = flags + (tid & 31);
                const unsigned target = (unsigned)(t + 1);
                for (int it = 0; it < (1 << 18); ++it) {   // capped: fail loud, not hang
                    if (ld_flag_l2(fp) == target) break;
                    __builtin_amdgcn_s_sleep(1);
                }
            }
            __syncthreads();
        }
    }
}

extern "C" void kernel_launch(void* const* d_in, const int* in_sizes, int n_in,
                              void* d_out, int out_size, void* d_ws, size_t ws_size,
                              hipStream_t stream) {
    const float* d_static = (const float*)d_in[0];
    const float* d_thr    = (const float*)d_in[1];
    const float* d_h0     = (const float*)d_in[2];
    const float* d_w1     = (const float*)d_in[3];

    float* out0 = (float*)d_out;                       // [64,2048,512]
    float* out1 = out0 + (size_t)TSTEPS * NK;          // [2048,512]
    float* out2 = out1 + NK;                           // [63,2048,512]

    _Float16* Wt    = (_Float16*)d_ws;                 // 1 MB
    _Float16* hbuf0 = Wt + (size_t)DR2 * 1024;         // 2 MB
    _Float16* hbuf1 = hbuf0 + NK;                      // 2 MB

    // barrier flags + claim counters: workspace tail (round-2 pass proves the
    // workspace path is taken; out1-tail fallback kept only as a last resort)
    size_t need = (size_t)1048576 + 4194304 + 4096;
    unsigned* bar = (ws_size >= need) ? (unsigned*)(hbuf1 + NK)
                                      : (unsigned*)(out1 + NK - 1024);

    prep_w<<<2048, 256, 0, stream>>>(d_w1, Wt, bar);
    prep_h0<<<1024, 256, 0, stream>>>(d_h0, hbuf0, out0);
    run_steps<<<NWG, 512, 0, stream>>>(d_thr, Wt, d_h0, d_static,
                                       hbuf0, hbuf1, out0, out1, out2, bar);
}

// Round 4
// 1485.179 us; speedup vs baseline: 946.1138x; 946.1138x over previous
//
#include <hip/hip_runtime.h>

#define NROWS 2048
#define DR2   512
#define TSTEPS 64
#define NK    ((size_t)NROWS * DR2)          // elements per [N,512] slice
#define NWG   256                            // persistent grid: 1 WG/CU (128 KB LDS)

typedef _Float16 half8 __attribute__((ext_vector_type(8)));
typedef float floatx4 __attribute__((ext_vector_type(4)));

// Async global->LDS, 16 B/lane. LDS base wave-uniform; HW scatters lane i at
// base + 16*i. Bank-conflict swizzle is applied on the GLOBAL address side.
static __device__ __forceinline__ void gload_lds16(const _Float16* g, _Float16* l) {
    __builtin_amdgcn_global_load_lds(
        (const __attribute__((address_space(1))) unsigned int*)g,
        (__attribute__((address_space(3))) unsigned int*)l,
        16, 0, 0);
}
// SC0 variant for h (produced each step by other CUs of the SAME XCD; data is
// in the shared XCD L2 — sc0 requests L1 bypass; the per-step acquire fence
// below is the architectural guarantee either way).
static __device__ __forceinline__ void gload_lds16_sc0(const _Float16* g, _Float16* l) {
    __builtin_amdgcn_global_load_lds(
        (const __attribute__((address_space(1))) unsigned int*)g,
        (__attribute__((address_space(3))) unsigned int*)l,
        16, 0, 1);
}

// Wt[j][kk] = w1[kk][j], f16, j in [0,512), kk in [0,1024).
// kk<512 multiplies h (top), kk>=512 multiplies static (bottom).
// Also zeroes barrier flags (8 XCDs x 32 slots x 16-dword stride) + claims.
__global__ void prep_w(const float* __restrict__ w1, _Float16* __restrict__ Wt,
                       unsigned* bar) {
    if (blockIdx.x == 0)
        for (int i = threadIdx.x; i < 4352; i += 256) bar[i] = 0u;
    int idx = blockIdx.x * 256 + threadIdx.x;   // = j*1024 + kk
    int kk = idx & 1023;
    int j  = idx >> 10;
    Wt[idx] = (_Float16)w1[kk * DR2 + j];
}

// h16 = (f16)h0 ; out0[0] = h0 (reference stores h0, NOT states[0])
__global__ void prep_h0(const float* __restrict__ h0, _Float16* __restrict__ h16,
                        float* __restrict__ out0) {
    int idx = blockIdx.x * 256 + threadIdx.x;   // per float4
    float4 v = ((const float4*)h0)[idx];
    ((float4*)out0)[idx] = v;
    union { uint2 u; _Float16 h[4]; } p;
    p.h[0] = (_Float16)v.x; p.h[1] = (_Float16)v.y;
    p.h[2] = (_Float16)v.z; p.h[3] = (_Float16)v.w;
    ((uint2*)h16)[idx] = p.u;
}

// ---------------------------------------------------------------------------
// Persistent kernel, XCD-local recurrence. Each physical XCD (HW_REG_XCC_ID,
// slot claimed via device atomicAdd) owns 256 rows: 32 WGs = 16 j-blocks x 2
// row-groups of 128. h ping-pong stays inside the XCD's L2.
// Barrier repair vs round 3 (which spun to cap every step — hand-rolled sc0
// polls read a never-evicted stale L1 line):
//   release: __syncthreads (vmcnt(0) -> write-through h stores are in L2),
//            then tid0 RELAXED agent atomic flag store (L2-point op).
//   arrive:  lanes 0..31 poll via RELAXED agent atomic fetch_add(+0) — RMWs
//            execute at the L2 coherence point, architecturally L1-proof.
//   acquire: ONE wave-0 acquire-agent fence per WG per step (L1 invalidate)
//            so next step's h loads cannot hit stale L1 lines.
// No ACQ_REL RMWs, no per-thread threadfence, no wbl2 storms.
// ---------------------------------------------------------------------------
__global__ __launch_bounds__(512, 1) void run_steps(
    const float* __restrict__ thr,       // [T,N]
    const _Float16* __restrict__ Wt,     // [512][1024]
    const float* __restrict__ h0,        // [N,512] f32
    const float* __restrict__ sta,       // [T,N,512] f32
    _Float16* __restrict__ hb0,          // [N,512] f16 ping
    _Float16* __restrict__ hb1,          // [N,512] f16 pong
    float* __restrict__ out0, float* __restrict__ out1, float* __restrict__ out2,
    unsigned* bar)                       // [0..4095] flags (64B stride), [4096..4103] claims
{
    __shared__ _Float16 Wres[32 * 1024];     // 64 KB, resident all 64 steps
    __shared__ _Float16 Abuf[2][128 * 128];  // 2 x 32 KB, K-phase double buffer
    __shared__ unsigned slot_sh;

    const int tid = threadIdx.x, lane = tid & 63, wv = tid >> 6;
    const int lm = lane & 15, quad = lane >> 4;

    // physical placement (HW_REG_XCC_ID = id 20, offset 0, size 32; m09)
    const unsigned xcd = (unsigned)__builtin_amdgcn_s_getreg(63508) & 7u;
    if (tid == 0) slot_sh = atomicAdd(bar + 4096 + xcd, 1u);  // device-scope
    __syncthreads();
    const unsigned slot = slot_sh;                 // 0..31 within this XCD
    const int j0 = (int)(slot & 15) * 32;
    const int n0 = ((int)xcd * 2 + (int)(slot >> 4)) * 128;
    unsigned* flags = bar + xcd * 512;             // 32 slots x 16 dwords (64 B)

    // one-time: full-W residency (32 j-rows x K=1024, swizzled global source)
    #pragma unroll
    for (int i = 0; i < 8; ++i) {
        int idx = i * 8 + wv;                      // 0..63
        int r = idx >> 1, hh = idx & 1;
        gload_lds16(Wt + (size_t)(j0 + r) * 1024 + hh * 512 + (lane ^ (r & 7)) * 8,
                    Wres + r * 1024 + hh * 512);
    }

    const int nb = n0 + wv * 16 + quad * 4;        // + r
    const int jb = j0 + lm;                        // + tj*16
    const int ra = wv * 16 + lm;                   // A row for MFMA reads
    float thv[4], thvn[4], hrv[2][4];
    #pragma unroll
    for (int r = 0; r < 4; ++r) {
        thv[r] = thr[nb + r];                      // t = 0
        #pragma unroll
        for (int tj = 0; tj < 2; ++tj)             // f16-roundtripped gate operand
            hrv[tj][r] = (float)(_Float16)h0[(size_t)(nb + r) * DR2 + jb + tj * 16];
    }

    const float DECAY = 0.60653065971263342f;

    #pragma unroll 1
    for (int t = 0; t < TSTEPS; ++t) {
        const _Float16* hcur = (t & 1) ? hb1 : hb0;
        _Float16*       hnx  = (t & 1) ? hb0 : hb1;
        const float*    stat = sta + (size_t)t * NK;

        // stage K-phase 0 of A (h rows n0..n0+127, K 0..127)
        #pragma unroll
        for (int i = 0; i < 4; ++i) {
            int rp = wv * 16 + i * 4;
            int r  = rp + (lane >> 4);
            int c  = (lane & 15) ^ (r & 7);
            gload_lds16_sc0(hcur + (size_t)(n0 + r) * DR2 + c * 8, &Abuf[0][rp * 128]);
        }
        __syncthreads();    // also drains Wres loads on t=0

        floatx4 acc[2] = {};

        #pragma unroll
        for (int p = 0; p < 8; ++p) {
            float4 pre[8];
            if (p < 3) {                           // prefetch next h phase
                #pragma unroll
                for (int i = 0; i < 4; ++i) {
                    int rp = wv * 16 + i * 4;
                    int r  = rp + (lane >> 4);
                    int c  = (lane & 15) ^ (r & 7);
                    gload_lds16_sc0(hcur + (size_t)(n0 + r) * DR2 + (p + 1) * 128 + c * 8,
                                    &Abuf[(p + 1) & 1][rp * 128]);
                }
            } else if (p < 7) {                    // issue static f32 loads early
                #pragma unroll
                for (int q = 0; q < 4; ++q) {
                    int cidx = q * 512 + tid;      // 0..2047 = 128 rows x 16 chunks
                    int r = cidx >> 4, c16 = cidx & 15;
                    int k8 = c16 ^ (r & 7);
                    const float* g = stat + (size_t)(n0 + r) * DR2 + (p - 3) * 128 + k8 * 8;
                    pre[q * 2]     = *(const float4*)g;
                    pre[q * 2 + 1] = *(const float4*)(g + 4);
                }
            }
            if (p == 0 && t < TSTEPS - 1) {        // prefetch next-step thr
                #pragma unroll
                for (int r = 0; r < 4; ++r)
                    thvn[r] = thr[(t + 1) * NROWS + nb + r];
            }

            const _Float16* A = Abuf[p & 1];
            #pragma unroll
            for (int ks = 0; ks < 4; ++ks) {
                int c8 = ks * 4 + quad;            // phase-local chunk 0..15
                int cg = p * 16 + c8;              // global K chunk 0..127
                half8 a  = *(const half8*)(A + ra * 128 + ((c8 ^ (ra & 7)) << 3));
                half8 b0 = *(const half8*)(Wres + lm * 1024 + ((cg ^ (lm & 7)) << 3));
                half8 b1 = *(const half8*)(Wres + (lm + 16) * 1024 + ((cg ^ (lm & 7)) << 3));
                acc[0] = __builtin_amdgcn_mfma_f32_16x16x32_f16(a, b0, acc[0], 0, 0, 0);
                acc[1] = __builtin_amdgcn_mfma_f32_16x16x32_f16(a, b1, acc[1], 0, 0, 0);
            }

            if (p >= 3 && p < 7) {                 // cvt + ds_write static phase
                #pragma unroll
                for (int q = 0; q < 4; ++q) {
                    int cidx = q * 512 + tid;
                    int r = cidx >> 4, c16 = cidx & 15;
                    float4 lo = pre[q * 2], hi = pre[q * 2 + 1];
                    union { half8 v; _Float16 h[8]; } u;
                    u.h[0]=(_Float16)lo.x; u.h[1]=(_Float16)lo.y;
                    u.h[2]=(_Float16)lo.z; u.h[3]=(_Float16)lo.w;
                    u.h[4]=(_Float16)hi.x; u.h[5]=(_Float16)hi.y;
                    u.h[6]=(_Float16)hi.z; u.h[7]=(_Float16)hi.w;
                    *(half8*)(&Abuf[(p + 1) & 1][r * 128 + (c16 << 3)]) = u.v;
                }
            }
            if (p < 7) __syncthreads();
        }

        // epilogue: gate; outputs written immediately (pure, no aliasing)
        #pragma unroll
        for (int r = 0; r < 4; ++r) {
            float th = thv[r], om = 1.0f - th;
            #pragma unroll
            for (int tj = 0; tj < 2; ++tj) {
                float z  = acc[tj][r] * th + hrv[tj][r] * om;
                float hn = DECAY / (1.0f + __expf(-z));
                _Float16 h16 = (_Float16)hn;
                if (t < TSTEPS - 1)                // next step's input (local L2)
                    hnx[(size_t)(nb + r) * DR2 + jb + tj * 16] = h16;
                if (t >= 1) {
                    size_t o = ((size_t)t * NROWS + nb + r) * DR2 + jb + tj * 16;
                    __builtin_nontemporal_store(hn, out0 + o);
                    __builtin_nontemporal_store(hn - hrv[tj][r], out2 + (o - NK));
                }
                if (t == TSTEPS - 1)
                    __builtin_nontemporal_store(
                        hn, out1 + (size_t)(nb + r) * DR2 + jb + tj * 16);
                hrv[tj][r] = (float)h16;           // f16-roundtripped carry
            }
            if (t < TSTEPS - 1) thv[r] = thvn[r];
        }

        // ---- XCD-local barrier (atomic flags at the L2 coherence point) ----
        if (t < TSTEPS - 1) {
            __syncthreads();   // emits s_waitcnt vmcnt(0): h stores are in L2
            const unsigned target = (unsigned)(t + 1);
            if (tid == 0)
                __hip_atomic_store(flags + slot * 16, target,
                                   __ATOMIC_RELAXED, __HIP_MEMORY_SCOPE_AGENT);
            if (tid < 64) {
                if (tid < 32) {                    // one lane per peer slot
                    unsigned* fp = flags + tid * 16;
                    for (int it = 0; it < (1 << 16); ++it) {   // capped: fail loud
                        if (__hip_atomic_fetch_add(fp, 0u, __ATOMIC_RELAXED,
                                                   __HIP_MEMORY_SCOPE_AGENT) >= target)
                            break;
                        __builtin_amdgcn_s_sleep(1);
                    }
                }
                // one acquire per WG: invalidate stale L1 lines before the
                // next step's h loads (wave-level cache op, CU-local cost)
                __builtin_amdgcn_fence(__ATOMIC_ACQUIRE, "agent");
            }
            __syncthreads();
        }
    }
}

extern "C" void kernel_launch(void* const* d_in, const int* in_sizes, int n_in,
                              void* d_out, int out_size, void* d_ws, size_t ws_size,
                              hipStream_t stream) {
    const float* d_static = (const float*)d_in[0];
    const float* d_thr    = (const float*)d_in[1];
    const float* d_h0     = (const float*)d_in[2];
    const float* d_w1     = (const float*)d_in[3];

    float* out0 = (float*)d_out;                       // [64,2048,512]
    float* out1 = out0 + (size_t)TSTEPS * NK;          // [2048,512]
    float* out2 = out1 + NK;                           // [63,2048,512]

    _Float16* Wt    = (_Float16*)d_ws;                 // 1 MB
    _Float16* hbuf0 = Wt + (size_t)DR2 * 1024;         // 2 MB
    _Float16* hbuf1 = hbuf0 + NK;                      // 2 MB

    // barrier flags (8 x 32 x 64B) + claim counters: workspace tail
    size_t need = (size_t)1048576 + 4194304 + 17408 + 64;
    unsigned* bar = (ws_size >= need) ? (unsigned*)(hbuf1 + NK)
                                      : (unsigned*)(out1 + NK - 4608);

    prep_w<<<2048, 256, 0, stream>>>(d_w1, Wt, bar);
    prep_h0<<<1024, 256, 0, stream>>>(d_h0, hbuf0, out0);
    run_steps<<<NWG, 512, 0, stream>>>(d_thr, Wt, d_h0, d_static,
                                       hbuf0, hbuf1, out0, out1, out2, bar);
}